// Round 19
// baseline (25.850 us; speedup 1.0000x reference)
//
#include <hip/hip_runtime.h>
#include <math.h>

#define NB 4
#define NN 512
#define ND 128
#define NC 10
#define NT 32                // 16-wide tiles per side
#define MREP 2               // i-tiles per wave
#define NBLK_M (NB*NT*4)     // 512 blocks: (b, Tj, q); q = octet of i-tiles

typedef short    bf16x8 __attribute__((ext_vector_type(8)));
typedef unsigned u32x4  __attribute__((ext_vector_type(4)));
typedef float    f32x4  __attribute__((ext_vector_type(4)));

// pack two f32 into two RNE bf16 (low short = a, high short = b)
static __device__ __forceinline__ unsigned pack_bf2(float a, float b) {
    unsigned short la = __builtin_bit_cast(unsigned short, (__bf16)a);
    unsigned short hb = __builtin_bit_cast(unsigned short, (__bf16)b);
    return (unsigned)la | ((unsigned)hb << 16);
}

// r18 math (single-MFMA bf16, RNE packs) + W staged in LDS (removes the 80
// per-wave VMEM W-loads from the B-build critical chain; ds_read ~40cy vs
// L1/L2 ~100-200cy) + x loads/A-conversion hoisted above the staging barrier.
// Frag semantics (r9-r18 verified, absmax 256 vs thr 17694):
//   A-frag (g): lane l holds x[row = Ti*16 + (l&15)][d = 32g + 8*(l>>4) + e]
//   B-frag (c,g): lane l holds y_c[col = Tj*16 + (l&15)][same d-enumeration]
//   C/D: col = lane&15, row = (lane>>4)*4 + reg
__global__ __launch_bounds__(256) void w2ner_fused(
    const float* __restrict__ x, const int* __restrict__ span,
    const int* __restrict__ seqlen, const float* __restrict__ Wm,
    const float* __restrict__ bias, float* __restrict__ out,
    float* __restrict__ accum)
{
    __shared__ float sW[ND * NC];     // 5 KB, row-major [d][c]
    __shared__ float sRed[4 * 5];

    const int tid = threadIdx.x;
    const int blk = blockIdx.x;
    const int q  = blk & 3;
    const int Tj = (blk >> 2) & 31;
    const int b  = blk >> 7;
    const int wv = tid >> 6, l = tid & 63;
    const int jl = l & 15, kg = l >> 4;       // kg doubles as C/D row-group
    const int Ti0 = q * 8 + wv * MREP;
    const int j  = Tj * 16 + jl;
    const int sl = seqlen[b];
    const float* xb = x + (size_t)b * NN * ND;
    const size_t sb = (size_t)b * NN * NN;

    // ---- stage W into LDS (coalesced: 20 contiguous floats per thread) ----
    #pragma unroll
    for (int t5 = 0; t5 < 5; ++t5) {
        const int idx = t5 * 256 + tid;       // 1280 floats
        sW[idx] = Wm[idx];
    }

    // ---- hoisted x loads; A-frags converted immediately (latency overlaps staging) ----
    bf16x8 ah[MREP][4];
    float  xj[4][8];
    #pragma unroll
    for (int g = 0; g < 4; ++g) {
        const int d0 = 32 * g + 8 * kg;
        #pragma unroll
        for (int m = 0; m < MREP; ++m) {
            const int irow = (Ti0 + m) * 16 + jl;
            float xiv[8];
            *(float4*)&xiv[0] = *(const float4*)(xb + (size_t)irow * ND + d0);
            *(float4*)&xiv[4] = *(const float4*)(xb + (size_t)irow * ND + d0 + 4);
            u32x4 ahw;
            #pragma unroll
            for (int e2 = 0; e2 < 4; ++e2)
                ahw[e2] = pack_bf2(xiv[2 * e2], xiv[2 * e2 + 1]);
            ah[m][g] = __builtin_bit_cast(bf16x8, ahw);
        }
        *(float4*)&xj[g][0] = *(const float4*)(xb + (size_t)j * ND + d0);
        *(float4*)&xj[g][4] = *(const float4*)(xb + (size_t)j * ND + d0 + 4);
    }

    // span prefetch for the 8 pairs this lane owns
    int sp[MREP][4];
    #pragma unroll
    for (int m = 0; m < MREP; ++m) {
        const int ib = (Ti0 + m) * 16 + kg * 4;
        #pragma unroll
        for (int r = 0; r < 4; ++r)
            sp[m][r] = span[sb + (size_t)(ib + r) * NN + j];
    }

    // bias folded into accumulator init (MFMA C-in)
    f32x4 acc[MREP][NC];
    #pragma unroll
    for (int c = 0; c < NC; ++c) {
        const float bc = bias[c];
        #pragma unroll
        for (int m = 0; m < MREP; ++m) acc[m][c] = (f32x4){bc, bc, bc, bc};
    }

    __syncthreads();   // sW ready

    #pragma unroll
    for (int g = 0; g < 4; ++g) {
        const int d0 = 32 * g + 8 * kg;

        // B fragments (one per class): y = x_j * W, RNE to bf16; W from LDS
        u32x4 yw[NC];
        #pragma unroll
        for (int e2 = 0; e2 < 4; ++e2) {
            float wb[20];   // W rows d0+2e2, d0+2e2+1
            const float4* wp = (const float4*)(sW + (d0 + 2 * e2) * NC);
            #pragma unroll
            for (int t5 = 0; t5 < 5; ++t5) *(float4*)&wb[4 * t5] = wp[t5];
            const float x0 = xj[g][2 * e2], x1 = xj[g][2 * e2 + 1];
            #pragma unroll
            for (int c = 0; c < NC; ++c)
                yw[c][e2] = pack_bf2(x0 * wb[c], x1 * wb[10 + c]);
        }

        // single MFMA per (c, m)
        #pragma unroll
        for (int c = 0; c < NC; ++c) {
            const bf16x8 bh = __builtin_bit_cast(bf16x8, yw[c]);
            #pragma unroll
            for (int m = 0; m < MREP; ++m)
                acc[m][c] = __builtin_amdgcn_mfma_f32_16x16x32_bf16(ah[m][g], bh, acc[m][c], 0, 0, 0);
        }
    }

    // fused softmax/focal epilogue (identical to r18)
    float lsum = 0.f, accn = 0.f, tpn = 0.f, tnn = 0.f, fpn = 0.f;
    #pragma unroll
    for (int m = 0; m < MREP; ++m) {
        const int ib = (Ti0 + m) * 16 + kg * 4;
        #pragma unroll
        for (int r = 0; r < 4; ++r) {
            const int i = ib + r;
            float L[NC];
            #pragma unroll
            for (int c = 0; c < NC; ++c) L[c] = acc[m][c][r];   // bias already in
            int am = 0; float mx = L[0];
            #pragma unroll
            for (int c = 1; c < NC; ++c) { if (L[c] > mx) { mx = L[c]; am = c; } }  // first-occurrence argmax
            float e[NC]; float s = 0.f;
            #pragma unroll
            for (int c = 0; c < NC; ++c) { e[c] = __expf(L[c] - mx); s += e[c]; }
            const int spv = sp[m][r];
            float lsp = L[0], esp = e[0];
            #pragma unroll
            for (int c = 1; c < NC; ++c) {
                lsp = (spv == c) ? L[c] : lsp;
                esp = (spv == c) ? e[c] : esp;
            }
            const float inv  = __builtin_amdgcn_rcpf(s);
            const float lp   = (lsp - mx) - __logf(s);
            const float prob = esp * inv;
            const float om   = 1.f - prob;
            const float lm   = -(om * om) * lp;
            const bool v = (i < sl) && (j < sl);
            const int pred = v ? am : 0;
            out[sb + (size_t)i * NN + j] = (float)pred;
            if (v) { lsum += lm; if (pred == spv) accn += 1.f; }
            if (spv > 0) { if (pred == spv) tpn += 1.f; else tnn += 1.f; }
            else if (pred > 0 && v) fpn += 1.f;
        }
    }

    // block reduction -> per-block slot, SoA layout accum[k][blk]
    float vals[5] = { lsum, accn, tpn, tnn, fpn };
    #pragma unroll
    for (int k = 0; k < 5; ++k) {
        float vv = vals[k];
        for (int o = 32; o > 0; o >>= 1) vv += __shfl_down(vv, o);
        vals[k] = vv;
    }
    if (l == 0) {
        #pragma unroll
        for (int k = 0; k < 5; ++k) sRed[wv * 5 + k] = vals[k];
    }
    __syncthreads();
    if (tid < 5) {
        accum[(size_t)tid * NBLK_M + blk] =
            sRed[tid] + sRed[5 + tid] + sRed[10 + tid] + sRed[15 + tid];
    }
}

__global__ __launch_bounds__(512) void w2ner_final(
    const int* __restrict__ seqlen, const float* __restrict__ accum,
    float* __restrict__ out)
{
    __shared__ float sP[8][5];
    const int tid = threadIdx.x;     // 512 threads == NBLK_M slots
    float part[5];
    #pragma unroll
    for (int k = 0; k < 5; ++k) part[k] = accum[(size_t)k * NBLK_M + tid];  // coalesced
    #pragma unroll
    for (int k = 0; k < 5; ++k) {
        float v = part[k];
        for (int o = 32; o > 0; o >>= 1) v += __shfl_down(v, o);
        part[k] = v;
    }
    const int wave = tid >> 6;
    const int lane = tid & 63;
    if (lane == 0) {
        #pragma unroll
        for (int k = 0; k < 5; ++k) sP[wave][k] = part[k];
    }
    __syncthreads();
    if (tid == 0) {
        float t[5];
        #pragma unroll
        for (int k = 0; k < 5; ++k) {
            float s = 0.f;
            #pragma unroll
            for (int w = 0; w < 8; ++w) s += sP[w][k];
            t[k] = s;
        }
        float s2 = 0.f;
        for (int k = 0; k < NB; ++k) { float s = (float)seqlen[k]; s2 += s * s; }
        const size_t base = (size_t)NB * NN * NN;
        out[base + 0] = t[2];          // tp
        out[base + 1] = t[3];          // tn
        out[base + 2] = t[4];          // fp
        out[base + 3] = t[0] / s2;     // loss
        out[base + 4] = t[1] / s2;     // accuracy
    }
}

extern "C" void kernel_launch(void* const* d_in, const int* in_sizes, int n_in,
                              void* d_out, int out_size, void* d_ws, size_t ws_size,
                              hipStream_t stream) {
    const float* x      = (const float*)d_in[0];
    const int*   span   = (const int*)d_in[1];
    const int*   seqlen = (const int*)d_in[2];
    const float* Wm     = (const float*)d_in[3];
    const float* bias   = (const float*)d_in[4];
    float* out   = (float*)d_out;
    float* accum = (float*)d_ws;   // 5*512 f32 SoA, fully overwritten each launch

    w2ner_fused<<<dim3(NBLK_M), 256, 0, stream>>>(x, span, seqlen, Wm, bias, out, accum);
    w2ner_final<<<1, 512, 0, stream>>>(seqlen, accum, out);
}